// Round 2
// baseline (4193.414 us; speedup 1.0000x reference)
//
#include <hip/hip_runtime.h>
#include <math.h>

// Problem constants
#define NB   16
#define CC   256
#define NPTS 16384       // 16*32*32
#define KK   8192
#define Z_OUT 4194304    // NPTS*CC
// d_out: [0,Z_OUT) z_q_out (BCHW), [Z_OUT,Z_OUT+NPTS) idx as float, [Z_OUT+NPTS] loss

// ws layout (floats)
#define WS_ZNORM 64
#define WS_ENORM 16448
#define WS_ET    32768   // eT[c][k], 8 MB

__device__ __forceinline__ void gl_lds16(const float* g, float* l) {
    __builtin_amdgcn_global_load_lds((const __attribute__((address_space(1))) void*)g,
                                     (__attribute__((address_space(3))) void*)l, 16, 0, 0);
}

// ---------------- K0a: znorm + zero loss accumulator ----------------
__global__ void k_znorm(const float* __restrict__ z, float* __restrict__ znorm,
                        float* __restrict__ lossAcc) {
    const int n  = blockIdx.x * 256 + threadIdx.x;
    const int b  = n >> 10, hw = n & 1023;
    const float* p = z + (size_t)b * 262144 + hw;
    float s = 0.0f;
#pragma unroll 8
    for (int c = 0; c < CC; ++c) {
        float v = p[(size_t)c * 1024];
        s = fmaf(v, v, s);
    }
    znorm[n] = s;
    if (n == 0) lossAcc[0] = 0.0f;
}

// ---------------- K0b: transpose emb[k][c] -> eT[c][k] ----------------
__global__ void k_transpose(const float* __restrict__ emb, float* __restrict__ eT) {
    __shared__ float ts[64][65];
    const int k0 = blockIdx.x * 64;
    const int c0 = blockIdx.y * 64;
    const int tid = threadIdx.x;
#pragma unroll
    for (int p = 0; p < 4; ++p) {
        int u = p * 256 + tid;
        int i = u >> 4, j4 = (u & 15) << 2;
        float4 v = *(const float4*)(emb + (size_t)(k0 + i) * CC + c0 + j4);
        ts[i][j4 + 0] = v.x; ts[i][j4 + 1] = v.y; ts[i][j4 + 2] = v.z; ts[i][j4 + 3] = v.w;
    }
    __syncthreads();
#pragma unroll
    for (int p = 0; p < 4; ++p) {
        int u = p * 256 + tid;
        int j = u >> 4, i4 = (u & 15) << 2;
        float4 v = make_float4(ts[i4 + 0][j], ts[i4 + 1][j], ts[i4 + 2][j], ts[i4 + 3][j]);
        *(float4*)(eT + (size_t)(c0 + j) * KK + k0 + i4) = v;
    }
}

// ---------------- K0c: enorm ----------------
__global__ void k_enorm(const float* __restrict__ emb, float* __restrict__ enorm) {
    const int w = threadIdx.x >> 6, lane = threadIdx.x & 63;
    const int k = blockIdx.x * 4 + w;
    float4 v = *(const float4*)(emb + (size_t)k * CC + lane * 4);
    float s = v.x * v.x + v.y * v.y + v.z * v.z + v.w * v.w;
    for (int off = 32; off > 0; off >>= 1) s += __shfl_down(s, off);
    if (lane == 0) enorm[k] = s;
}

// ---------------- K1: fused GEMM-distance + argmin ----------------
// 256 blocks x 512 threads (8 waves). Block = 64 n; thread tile 8n x 16k.
// K-pass = 1024 k (8 passes); c-chunks of 16, double-buffered LDS.
// es layout (per buf): f2 = c*1024 + q*256 + kg*4 + r   (c<16, q<4, kg<64, r<4)
// zs layout (per buf): c*64 + m                          (c<16, m<64)
#define ES_BUF 16384   // floats per es buffer
#define ZS_BUF 1024    // floats per zs buffer

__global__ __launch_bounds__(512, 2)
void k_argmin(const float* __restrict__ z, const float* __restrict__ eT,
              const float* __restrict__ znorm, const float* __restrict__ enorm,
              float* __restrict__ idx_out) {
    __shared__ float es[2 * ES_BUF];   // 128 KB
    __shared__ float zs[2 * ZS_BUF];   // 8 KB
    const int tid  = threadIdx.x;
    const int lane = tid & 63;
    const int w    = tid >> 6;         // wave 0..7
    const int kg   = tid >> 3;         // 0..63 (16 k's each)
    const int ng   = tid & 7;          // 0..7  (8 n's each)
    const int nb   = blockIdx.x << 6;
    const float* zbase = z + (size_t)(nb >> 10) * 262144 + (nb & 1023);

    // thread's 8 znorm values
    float zn[8];
    {
        float4 a = *(const float4*)(znorm + nb + ng * 8);
        float4 b = *(const float4*)(znorm + nb + ng * 8 + 4);
        zn[0]=a.x; zn[1]=a.y; zn[2]=a.z; zn[3]=a.w; zn[4]=b.x; zn[5]=b.y; zn[6]=b.z; zn[7]=b.w;
    }

    float bv[8]; int bi[8];
#pragma unroll
    for (int i = 0; i < 8; ++i) { bv[i] = __builtin_inff(); bi[i] = 0; }

    // stage chunk t into buf t&1
    auto stage = [&](int t) {
        const int pass = t >> 4, chunk = t & 15;
        const int c0 = chunk * 16, k0 = pass * 1024;
        float* esb = es + (size_t)(t & 1) * ES_BUF;
        float* zsb = zs + (size_t)(t & 1) * ZS_BUF;
        // e: wave w stages local c rows 2w, 2w+1 (4 q-loads each)
#pragma unroll
        for (int r = 0; r < 2; ++r) {
            const int c = 2 * w + r;
            const float* grow = eT + (size_t)(c0 + c) * KK + k0 + lane * 16;
            float* lb = esb + c * 1024;
            gl_lds16(grow + 0,  lb + 0);
            gl_lds16(grow + 4,  lb + 256);
            gl_lds16(grow + 8,  lb + 512);
            gl_lds16(grow + 12, lb + 768);
        }
        // z: waves 0..3, 4 c-rows each (64 consecutive n, 4 floats/lane)
        if (w < 4) {
            const float* g = zbase + (size_t)(c0 + w * 4 + (lane >> 4)) * 1024 + (lane & 15) * 4;
            gl_lds16(g, zsb + w * 256);
        }
    };

    stage(0);

    int t = 0;
#pragma unroll 1
    for (int pass = 0; pass < 8; ++pass) {
        float acc[128];
#pragma unroll
        for (int x = 0; x < 128; ++x) acc[x] = 0.0f;

#pragma unroll 1
        for (int chunk = 0; chunk < 16; ++chunk, ++t) {
            __syncthreads();                 // drains staging for buf t&1
            if (t + 1 < 128) stage(t + 1);
            const float* eb = es + (size_t)(t & 1) * ES_BUF + kg * 4;
            const float* zb = zs + (size_t)(t & 1) * ZS_BUF + ng * 8;
#pragma unroll
            for (int c = 0; c < 16; ++c) {
                const float4 za = *(const float4*)(zb + c * 64);
                const float4 zb4 = *(const float4*)(zb + c * 64 + 4);
                const float4 e0 = *(const float4*)(eb + c * 1024);
                const float4 e1 = *(const float4*)(eb + c * 1024 + 256);
                const float4 e2 = *(const float4*)(eb + c * 1024 + 512);
                const float4 e3 = *(const float4*)(eb + c * 1024 + 768);
                const float zv[8] = {za.x, za.y, za.z, za.w, zb4.x, zb4.y, zb4.z, zb4.w};
                const float ev[16] = {e0.x, e0.y, e0.z, e0.w, e1.x, e1.y, e1.z, e1.w,
                                      e2.x, e2.y, e2.z, e2.w, e3.x, e3.y, e3.z, e3.w};
#pragma unroll
                for (int i = 0; i < 8; ++i)
#pragma unroll
                    for (int j = 0; j < 16; ++j)
                        acc[i * 16 + j] = fmaf(zv[i], ev[j], acc[i * 16 + j]);
            }
        }

        // epilogue for this pass: d = (zn + en) - 2*dot, ascending k
        const int k0b = pass * 1024 + kg * 16;
        const float4 n0 = *(const float4*)(enorm + k0b);
        const float4 n1 = *(const float4*)(enorm + k0b + 4);
        const float4 n2 = *(const float4*)(enorm + k0b + 8);
        const float4 n3 = *(const float4*)(enorm + k0b + 12);
        const float en[16] = {n0.x, n0.y, n0.z, n0.w, n1.x, n1.y, n1.z, n1.w,
                              n2.x, n2.y, n2.z, n2.w, n3.x, n3.y, n3.z, n3.w};
#pragma unroll
        for (int i = 0; i < 8; ++i) {
#pragma unroll
            for (int j = 0; j < 16; ++j) {
                const float tt = zn[i] + en[j];
                const float d = tt - (acc[i * 16 + j] + acc[i * 16 + j]);
                if (d < bv[i]) { bv[i] = d; bi[i] = k0b + j; }
            }
        }
    }

    // cross-thread argmin reduce (reuse es buf0: 8 KB v + 8 KB i)
    __syncthreads();
    float* redv = es;
    int*   redi = (int*)(es + 4096);
#pragma unroll
    for (int i = 0; i < 8; ++i) {
        redv[kg * 64 + ng * 8 + i] = bv[i];
        redi[kg * 64 + ng * 8 + i] = bi[i];
    }
    __syncthreads();
    if (tid < 64) {
        float v = redv[tid];
        int   ib = redi[tid];
#pragma unroll 8
        for (int g = 1; g < 64; ++g) {
            float v2 = redv[g * 64 + tid];
            int   i2 = redi[g * 64 + tid];
            if (v2 < v || (v2 == v && i2 < ib)) { v = v2; ib = i2; }
        }
        idx_out[nb + tid] = (float)ib;
    }
}

// ---------------- K3: gather z_q (BCHW) + loss partials ----------------
__global__ void k_gather(const float* __restrict__ z, const float* __restrict__ emb,
                         const float* __restrict__ idxf, float* __restrict__ out,
                         float* __restrict__ lossAcc) {
    __shared__ float red[256];
    const int bid = blockIdx.x;
    const int b = bid >> 5, h = bid & 31;
    const int t = threadIdx.x;
    const int w_ = t & 31, cg = t >> 5;
    const int n = b * 1024 + h * 32 + w_;
    const int ki = (int)idxf[n];
    const float* ep = emb + (size_t)ki * CC;
    const size_t base = (size_t)b * 262144 + h * 32 + w_;
    float ls = 0.0f;
#pragma unroll 4
    for (int c = cg; c < CC; c += 8) {
        float e = ep[c];
        size_t a = base + (size_t)c * 1024;
        float zv = z[a];
        out[a] = e;
        float df = e - zv;
        ls = fmaf(df, df, ls);
    }
    red[t] = ls;
    __syncthreads();
    for (int s = 128; s > 0; s >>= 1) {
        if (t < s) red[t] += red[t + s];
        __syncthreads();
    }
    if (t == 0) atomicAdd(lossAcc, red[0]);
}

// ---------------- K4: finalize loss ----------------
__global__ void k_loss(const float* __restrict__ lossAcc, float* __restrict__ outLoss) {
    if (threadIdx.x == 0) {
        float m = lossAcc[0] * (1.0f / 4194304.0f);
        outLoss[0] = m + 0.25f * m;
    }
}

extern "C" void kernel_launch(void* const* d_in, const int* in_sizes, int n_in,
                              void* d_out, int out_size, void* d_ws, size_t ws_size,
                              hipStream_t stream) {
    const float* z   = (const float*)d_in[0];
    const float* emb = (const float*)d_in[1];
    float* outf = (float*)d_out;
    float* wsf  = (float*)d_ws;

    float* lossAcc = wsf;
    float* znorm   = wsf + WS_ZNORM;
    float* enorm   = wsf + WS_ENORM;
    float* eT      = wsf + WS_ET;

    k_znorm<<<64, 256, 0, stream>>>(z, znorm, lossAcc);
    k_transpose<<<dim3(128, 4), 256, 0, stream>>>(emb, eT);
    k_enorm<<<2048, 256, 0, stream>>>(emb, enorm);
    k_argmin<<<256, 512, 0, stream>>>(z, eT, znorm, enorm, outf + Z_OUT);
    k_gather<<<512, 256, 0, stream>>>(z, emb, outf + Z_OUT, outf, lossAcc);
    k_loss<<<1, 64, 0, stream>>>(lossAcc, outf + Z_OUT + NPTS);
}